// Round 20
// baseline (258.492 us; speedup 1.0000x reference)
//
#include <hip/hip_runtime.h>
#include <hip/hip_bf16.h>

#define HID 64
#define WPAD 68
#define NXCD 8
// fixed-capacity CSR: 64 slots/node (mean deg 16; P(deg>64) ~ 1e-20)

typedef float v2f __attribute__((ext_vector_type(2)));
typedef int v4i __attribute__((ext_vector_type(4)));

static __device__ __forceinline__ float bflo(unsigned u) { return __uint_as_float(u << 16); }
static __device__ __forceinline__ float bfhi(unsigned u) {
    return __uint_as_float(u & 0xFFFF0000u);
}
static __device__ __forceinline__ unsigned packbf(float a, float b) {
    __hip_bfloat16 ha = __float2bfloat16(a), hb = __float2bfloat16(b);
    unsigned short ua = *reinterpret_cast<unsigned short*>(&ha);
    unsigned short ub = *reinterpret_cast<unsigned short*>(&hb);
    return (unsigned)ua | ((unsigned)ub << 16);
}

// ---------------- fused count+fill into fixed-cap CSR ----------------
// XCD-partitioned by dst range (CSR stores stay in one local L2). Non-temporal
// edge-stream loads. 8 edges per thread-iteration -> 8 independent
// atomic->store chains in flight (probes atomic latency vs throughput bound).

__global__ __launch_bounds__(256) void fill_part(const int* __restrict__ ei, int E, int N,
                                                 int* __restrict__ cnt, int* __restrict__ csr) {
    int xcd = blockIdx.x & (NXCD - 1);
    int sl = blockIdx.x >> 3;
    int nsl = gridDim.x >> 3;
    int nlo = (int)((long long)N * xcd / NXCD);
    int nhi = (int)((long long)N * (xcd + 1) / NXCD);
    int stride = nsl * blockDim.x;
    int tid = sl * blockDim.x + threadIdx.x;
    const v4i* d4p = reinterpret_cast<const v4i*>(ei + E);
    int E8 = E >> 3;
    for (int i = tid; i < E8; i += stride) {
        v4i d4a = __builtin_nontemporal_load(&d4p[2 * i]);
        v4i d4b = __builtin_nontemporal_load(&d4p[2 * i + 1]);
        int dd[8] = {d4a[0], d4a[1], d4a[2], d4a[3], d4b[0], d4b[1], d4b[2], d4b[3]};
#pragma unroll
        for (int u = 0; u < 8; u++) {
            int d = dd[u];
            if (d >= nlo && d < nhi) {
                int s = __builtin_nontemporal_load(&ei[(i << 3) + u]);
                int pos = atomicAdd(&cnt[d], 1);
                csr[(d << 6) + pos] = s;
            }
        }
    }
    // tail (E % 8)
    for (int e = (E8 << 3) + tid; e < E; e += stride) {
        int d = ei[E + e];
        if (d >= nlo && d < nhi) {
            int pos = atomicAdd(&cnt[d], 1);
            csr[(d << 6) + pos] = ei[e];
        }
    }
}

// node_rec {deg, dinv_bits, batch, 0} + pre-scaled xs + zero pad rows + graph
// bounds (from sorted batch) -- one streaming pass, NO atomics.
__global__ void prep_kernel(const int* __restrict__ cnt, const float* __restrict__ x,
                            const int* __restrict__ batch, int4* __restrict__ rec,
                            float* __restrict__ xs, int* __restrict__ gb,
                            uint2* __restrict__ padA, uint2* __restrict__ padB, int N, int G) {
    int gid = blockIdx.x * blockDim.x + threadIdx.x;
    if (gid < 16) {
        padA[gid] = make_uint2(0u, 0u);
        padB[gid] = make_uint2(0u, 0u);
    }
    int stride = gridDim.x * blockDim.x;
    for (int n = gid; n < N; n += stride) {
        int deg = cnt[n];
        float dn = rsqrtf((float)(deg + 1));  // +1 self-loop
        int b = batch[n];
        rec[n] = make_int4(deg, __float_as_int(dn), b, 0);
        xs[n] = dn * x[n];
        // graph bounds: gb[g] = first node with batch >= g; gb[G] = N
        if (n == 0) {
            for (int g = 0; g <= b; g++) gb[g] = 0;
        } else {
            int pb = batch[n - 1];
            for (int g = pb + 1; g <= b; g++) gb[g] = n;
        }
        if (n == N - 1) {
            for (int g = b + 1; g <= G; g++) gb[g] = N;
        }
    }
}

// ---------------- piecewise-linear table for layer1 composite ----------------

__global__ void table_kernel(const float* __restrict__ W1, const float* __restrict__ b1,
                             const float* __restrict__ W2, float* __restrict__ tsort,
                             float* __restrict__ tabA, float* __restrict__ tabB) {
    int j = threadIdx.x;  // 64 threads = 1 wave
    float a = W1[j], b = b1[j];
    float t = (a != 0.f) ? (-b / a) : 3.4e38f;
    int rank = 0;
#pragma unroll 8
    for (int k = 0; k < 64; k++) {
        float tk = __shfl(t, k);
        rank += (tk < t) || (tk == t && k < j);
    }
    __shared__ float st[64];
    __shared__ int sperm[64];
    st[rank] = t;
    sperm[rank] = j;
    __syncthreads();
    tsort[j] = st[j];
    int f = j;
    float A = 0.f, B = 0.f;
#pragma unroll 4
    for (int k = 0; k < 64; k++) {
        float ak = W1[k], bk = b1[k], w = W2[k * 64 + f];
        if (ak < 0.f) { A += ak * w; B += bk * w; }
        else if (ak == 0.f && bk > 0.f) { B += bk * w; }
    }
    tabA[f] = A;
    tabB[f] = B;
#pragma unroll 4
    for (int s = 1; s <= 64; s++) {
        int jj = sperm[s - 1];
        float aj = W1[jj], bj = b1[jj], w = W2[jj * 64 + f];
        if (aj > 0.f) { A += aj * w; B += bj * w; }
        else if (aj < 0.f) { A -= aj * w; B -= bj * w; }
        tabA[s * 64 + f] = A;
        tabB[s * 64 + f] = B;
    }
}

// ---------------- LDS weight staging + packed quarter-split matmul ----------------

__device__ __forceinline__ void stageW(const float* __restrict__ W, float* __restrict__ sW) {
    for (int i = threadIdx.x; i < HID * HID; i += 256) {
        int r = i >> 6, c = i & 63;
        sW[r * WPAD + c] = W[i];
    }
    __syncthreads();
}

__device__ __forceinline__ void qmatmul(float4 h4, const float* __restrict__ sW, int q, int sl,
                                        v2f& z0, v2f& z1) {
    z0 = (v2f){0.f, 0.f};
    z1 = (v2f){0.f, 0.f};
#pragma unroll
    for (int t = 0; t < 16; t++) {
        int k = (q << 4) + t;
        int srclane = 20 * q + (t >> 2);
        float comp = ((t & 3) == 0) ? h4.x : ((t & 3) == 1) ? h4.y : ((t & 3) == 2) ? h4.z : h4.w;
        float hk = __shfl(comp, srclane);
        const v2f* w2 = reinterpret_cast<const v2f*>(&sW[k * WPAD + sl * 4]);
        z0 += hk * w2[0];  // v_pk_fma_f32
        z1 += hk * w2[1];
    }
#pragma unroll
    for (int off = 16; off <= 32; off <<= 1) {
        z0.x += __shfl_xor(z0.x, off);
        z0.y += __shfl_xor(z0.y, off);
        z1.x += __shfl_xor(z1.x, off);
        z1.y += __shfl_xor(z1.y, off);
    }
}

// ---------------- Layer 1: scalar propagate + table lookup -> bf16 z' ----------------

__global__ __launch_bounds__(256) void layer1_kernel(
    const float* __restrict__ xs, const int* __restrict__ csr, const int4* __restrict__ rec,
    const float* __restrict__ tsort, const float* __restrict__ tabA,
    const float* __restrict__ tabB, char* __restrict__ zb, int N) {
    int lane = threadIdx.x & 63;
    float tl = tsort[lane];  // one sorted breakpoint per lane
    int n = blockIdx.x * 4 + (threadIdx.x >> 6);
    if (n >= N) return;
    const int4 r = rec[n];
    float dn = __int_as_float(r.y);
    float acc = (lane < r.x) ? xs[csr[(n << 6) + lane]] : 0.f;
#pragma unroll
    for (int off = 32; off; off >>= 1) acc += __shfl_xor(acc, off);
    float p = dn * (acc + xs[n]);  // wave-uniform
    int s = __popcll(__ballot(tl <= p));
    float zf = dn * (p * tabA[s * 64 + lane] + tabB[s * 64 + lane]);
    float zo = __shfl_xor(zf, 1);  // partner feature
    if (!(lane & 1))
        *reinterpret_cast<unsigned*>(zb + (((size_t)n) << 7) + ((lane >> 1) << 2)) =
            packbf(zf, zo);
}

// ---------------- dual-node 64-wide propagate, 6-deep unroll ----------------
// 2 nodes/wave x 6-deep inner unroll = 12 independent gathers in flight at
// ~44-48 VGPR -> stays under the 64-VGPR occupancy cliff.
// FUSE: out' = dinv * (relu(P+bias) @ W) -> bf16   (layer 2)
// POOL: segmented LDS reduce over the block's 8 sorted nodes + fp32 atomic runs

template <bool FUSE, bool POOL>
__global__ __launch_bounds__(256) void p64_kernel(
    const char* __restrict__ zbase, const int* __restrict__ csr, const int4* __restrict__ rec,
    const float* __restrict__ bias, const float* __restrict__ W,
    uint2* __restrict__ outb, float* __restrict__ outp, int N) {
    __shared__ float sW[FUSE ? HID * WPAD : 1];
    __shared__ float pbuf[POOL ? 8 : 1][POOL ? HID : 1];
    __shared__ int pg[8];
    if (FUSE) stageW(W, sW);
    int lane = threadIdx.x & 63;
    int wid = threadIdx.x >> 6;
    int q = lane >> 4, sl = lane & 15;
    int nA = blockIdx.x * 8 + wid * 2;
    int nB = nA + 1;
    bool vA = nA < N, vB = nB < N;
    if (!POOL && !vA) return;
    unsigned soff = (unsigned)(sl << 3);

    int degA = vA ? rec[nA].x : 0;
    int degB = vB ? rec[nB].x : 0;
    int ewA = (lane < degA) ? csr[((vA ? nA : 0) << 6) + lane] : N;
    int ewB = (lane < degB) ? csr[((vB ? nB : 0) << 6) + lane] : N;
    int mtA = (degA + 3) >> 2, mtB = (degB + 3) >> 2;
    int mtmax = max(mtA, mtB);

    v2f a0A = {0.f, 0.f}, a1A = {0.f, 0.f};
    v2f a0B = {0.f, 0.f}, a1B = {0.f, 0.f};
    for (int tb = 0; tb < mtmax; tb += 6) {
#pragma unroll
        for (int u = 0; u < 6; u++) {
            int t = tb + u;
            int eidx = ((t << 2) + q) & 63;
            int sA = __shfl(ewA, eidx);
            int sB = __shfl(ewB, eidx);
            sA = (t < mtA) ? sA : N;  // wave-uniform predicate -> zero row
            sB = (t < mtB) ? sB : N;
            const uint2 ra = *reinterpret_cast<const uint2*>(
                zbase + (((unsigned)sA << 7) + soff));
            const uint2 rb = *reinterpret_cast<const uint2*>(
                zbase + (((unsigned)sB << 7) + soff));
            v2f u0 = {bflo(ra.x), bfhi(ra.x)};
            v2f u1 = {bflo(ra.y), bfhi(ra.y)};
            a0A += u0; a1A += u1;
            v2f w0 = {bflo(rb.x), bfhi(rb.x)};
            v2f w1 = {bflo(rb.y), bfhi(rb.y)};
            a0B += w0; a1B += w1;
        }
    }
#pragma unroll
    for (int off = 16; off <= 32; off <<= 1) {
        a0A.x += __shfl_xor(a0A.x, off); a0A.y += __shfl_xor(a0A.y, off);
        a1A.x += __shfl_xor(a1A.x, off); a1A.y += __shfl_xor(a1A.y, off);
        a0B.x += __shfl_xor(a0B.x, off); a0B.y += __shfl_xor(a0B.y, off);
        a1B.x += __shfl_xor(a1B.x, off); a1B.y += __shfl_xor(a1B.y, off);
    }
    // self terms (pre-scaled) + dinv[d] scale; rec reloaded post-loop (L2-hot)
    float dnA = __int_as_float(rec[vA ? nA : 0].y);
    float dnB = __int_as_float(rec[vB ? nB : 0].y);
    {
        const uint2 sa = *reinterpret_cast<const uint2*>(
            zbase + (((unsigned)(vA ? nA : N) << 7) + soff));
        a0A.x = dnA * (a0A.x + bflo(sa.x));
        a0A.y = dnA * (a0A.y + bfhi(sa.x));
        a1A.x = dnA * (a1A.x + bflo(sa.y));
        a1A.y = dnA * (a1A.y + bfhi(sa.y));
        const uint2 sb = *reinterpret_cast<const uint2*>(
            zbase + (((unsigned)(vB ? nB : N) << 7) + soff));
        a0B.x = dnB * (a0B.x + bflo(sb.x));
        a0B.y = dnB * (a0B.y + bfhi(sb.x));
        a1B.x = dnB * (a1B.x + bflo(sb.y));
        a1B.y = dnB * (a1B.y + bfhi(sb.y));
    }
    const float4 b4 = *reinterpret_cast<const float4*>(&bias[sl << 2]);

    if (FUSE) {
        float4 hA, hB;
        hA.x = fmaxf(a0A.x + b4.x, 0.f); hA.y = fmaxf(a0A.y + b4.y, 0.f);
        hA.z = fmaxf(a1A.x + b4.z, 0.f); hA.w = fmaxf(a1A.y + b4.w, 0.f);
        hB.x = fmaxf(a0B.x + b4.x, 0.f); hB.y = fmaxf(a0B.y + b4.y, 0.f);
        hB.z = fmaxf(a1B.x + b4.z, 0.f); hB.w = fmaxf(a1B.y + b4.w, 0.f);
        v2f zA0, zA1, zB0, zB1;
        qmatmul(hA, sW, q, sl, zA0, zA1);
        qmatmul(hB, sW, q, sl, zB0, zB1);
        if (q == 0) {
            if (vA)
                outb[(size_t)nA * 16 + sl] = make_uint2(packbf(dnA * zA0.x, dnA * zA0.y),
                                                        packbf(dnA * zA1.x, dnA * zA1.y));
            if (vB)
                outb[(size_t)nB * 16 + sl] = make_uint2(packbf(dnB * zB0.x, dnB * zB0.y),
                                                        packbf(dnB * zB1.x, dnB * zB1.y));
        }
    } else if (POOL) {
        if (q == 0) {
            *reinterpret_cast<float4*>(&pbuf[wid * 2][sl << 2]) =
                make_float4(a0A.x + b4.x, a0A.y + b4.y, a1A.x + b4.z, a1A.y + b4.w);
            *reinterpret_cast<float4*>(&pbuf[wid * 2 + 1][sl << 2]) =
                make_float4(a0B.x + b4.x, a0B.y + b4.y, a1B.x + b4.z, a1B.y + b4.w);
            if (sl == 0) {
                pg[wid * 2] = vA ? rec[nA].z : -1;
                pg[wid * 2 + 1] = vB ? rec[nB].z : -1;
            }
        }
        __syncthreads();
        if (wid == 0) {
            int j = lane;
            float v = 0.f;
            int gp = -1;
#pragma unroll
            for (int w = 0; w < 8; w++) {
                int gw = pg[w];  // wave-uniform
                if (gw < 0) continue;
                if (gw == gp) {
                    v += pbuf[w][j];
                } else {
                    if (gp >= 0) atomicAdd(&outp[(size_t)gp * HID + j], v);
                    v = pbuf[w][j];
                    gp = gw;
                }
            }
            if (gp >= 0) atomicAdd(&outp[(size_t)gp * HID + j], v);
        }
    }
}

// ---------------- head (counts from graph bounds) ----------------

__global__ void head_kernel(const float* __restrict__ psum, const int* __restrict__ gb,
                            const float* __restrict__ dist, const float* __restrict__ sw,
                            const float* __restrict__ Wl, const float* __restrict__ bl,
                            const float* __restrict__ Wl1, const float* __restrict__ bl1,
                            const float* __restrict__ Wl2, const float* __restrict__ bl2,
                            float* __restrict__ out, int G) {
    int g = blockIdx.x * blockDim.x + threadIdx.x;
    if (g >= G) return;
    int c = gb[g + 1] - gb[g];
    float invc = 1.f / fmaxf((float)c, 1.f);
    float a[5];
#pragma unroll
    for (int k = 0; k < 5; k++) a[k] = bl[k];
    for (int j = 0; j < HID; j++) {
        float p = psum[(size_t)g * HID + j] * invc;
#pragma unroll
        for (int k = 0; k < 5; k++) a[k] += p * Wl[j * 5 + k];
    }
    float g7[7];
#pragma unroll
    for (int k = 0; k < 5; k++) g7[k] = a[k];
    g7[5] = dist[g];
    g7[6] = sw[g];
    float r = bl2[0];
#pragma unroll
    for (int k2 = 0; k2 < 5; k2++) {
        float t = bl1[k2];
#pragma unroll
        for (int j = 0; j < 7; j++) t += g7[j] * Wl1[j * 5 + k2];
        t = fmaxf(t, 0.f);
        r += t * Wl2[k2];
    }
    out[g] = r;
}

// ---------------- launch ----------------

extern "C" void kernel_launch(void* const* d_in, const int* in_sizes, int n_in,
                              void* d_out, int out_size, void* d_ws, size_t ws_size,
                              hipStream_t stream) {
    const float* x    = (const float*)d_in[0];
    const int*   ei   = (const int*)d_in[1];
    const int*   batch= (const int*)d_in[2];
    const float* dist = (const float*)d_in[3];
    const float* sw   = (const float*)d_in[4];
    const float* W1   = (const float*)d_in[5];
    const float* b1   = (const float*)d_in[6];
    const float* W2   = (const float*)d_in[7];
    const float* b2   = (const float*)d_in[8];
    const float* W3   = (const float*)d_in[9];
    const float* b3   = (const float*)d_in[10];
    const float* Wl   = (const float*)d_in[11];
    const float* bl   = (const float*)d_in[12];
    const float* Wl1  = (const float*)d_in[13];
    const float* bl1  = (const float*)d_in[14];
    const float* Wl2  = (const float*)d_in[15];
    const float* bl2  = (const float*)d_in[16];

    int N = in_sizes[0];
    int E = in_sizes[1] / 2;
    int G = in_sizes[3];

    char* ws = (char*)d_ws;
    size_t off = 0;
    auto alloc = [&](size_t bytes) -> char* {
        char* p = ws + off;
        off += (bytes + 255) & ~(size_t)255;
        return p;
    };
    // contiguous zero-init region: cnt | psum
    char*  zreg      = ws;
    int*   cnt       = (int*)alloc((size_t)N * 4);
    float* psum      = (float*)alloc((size_t)G * HID * 4);
    size_t zbytes    = off;
    int4*  rec       = (int4*)alloc((size_t)N * 16);
    float* xs        = (float*)alloc((size_t)N * 4);
    int*   gb        = (int*)alloc(((size_t)G + 1) * 4);
    float* tsort     = (float*)alloc(64 * 4);
    float* tabA      = (float*)alloc(65 * 64 * 4);
    float* tabB      = (float*)alloc(65 * 64 * 4);
    char*  bufA      = alloc(((size_t)N + 1) * 128);   // bf16 rows + zero pad row N
    char*  bufB      = alloc(((size_t)N + 1) * 128);
    int*   csr       = (int*)alloc((size_t)N * 64 * 4);  // fixed-cap CSR, 64 slots/node

    (void)hipMemsetAsync(zreg, 0, zbytes, stream);

    table_kernel<<<1, 64, 0, stream>>>(W1, b1, W2, tsort, tabA, tabB);
    fill_part<<<2048, 256, 0, stream>>>(ei, E, N, cnt, csr);
    prep_kernel<<<(N + 255) / 256, 256, 0, stream>>>(
        cnt, x, batch, rec, xs, gb,
        (uint2*)(bufA + (size_t)N * 128), (uint2*)(bufB + (size_t)N * 128), N, G);

    int nb1 = (N + 3) / 4;
    int nb2 = (N + 7) / 8;
    layer1_kernel<<<nb1, 256, 0, stream>>>(xs, csr, rec, tsort, tabA, tabB, bufA, N);
    p64_kernel<true, false><<<nb2, 256, 0, stream>>>(bufA, csr, rec, b2, W3,
                                                     (uint2*)bufB, nullptr, N);
    p64_kernel<false, true><<<nb2, 256, 0, stream>>>(bufB, csr, rec, b3, nullptr,
                                                     nullptr, psum, N);
    head_kernel<<<(G + 255) / 256, 256, 0, stream>>>(psum, gb, dist, sw, Wl, bl, Wl1, bl1, Wl2,
                                                     bl2, (float*)d_out, G);
}

// Round 21
// 248.697 us; speedup vs baseline: 1.0394x; 1.0394x over previous
//
#include <hip/hip_runtime.h>
#include <hip/hip_bf16.h>

#define HID 64
#define WPAD 68
#define NXCD 8
// fixed-capacity CSR: 64 slots/node (mean deg 16; P(deg>64) ~ 1e-20)

typedef float v2f __attribute__((ext_vector_type(2)));

static __device__ __forceinline__ float bflo(unsigned u) { return __uint_as_float(u << 16); }
static __device__ __forceinline__ float bfhi(unsigned u) {
    return __uint_as_float(u & 0xFFFF0000u);
}
static __device__ __forceinline__ unsigned packbf(float a, float b) {
    __hip_bfloat16 ha = __float2bfloat16(a), hb = __float2bfloat16(b);
    unsigned short ua = *reinterpret_cast<unsigned short*>(&ha);
    unsigned short ub = *reinterpret_cast<unsigned short*>(&hb);
    return (unsigned)ua | ((unsigned)ub << 16);
}

// ---------------- fused count+fill into fixed-cap CSR (r14 best form) ----------------
// XCD-partitioned by dst range (atomics + stores in one local L2); plain cached
// strided loads (L2 keeps the dst stream hot across the 8 XCD replays);
// manual unroll-4 batched loads = 8 independent reads in flight per iter.

__global__ __launch_bounds__(256) void fill_part(const int* __restrict__ ei, int E, int N,
                                                 int* __restrict__ cnt, int* __restrict__ csr) {
    int xcd = blockIdx.x & (NXCD - 1);
    int sl = blockIdx.x >> 3;
    int nsl = gridDim.x >> 3;
    int nlo = (int)((long long)N * xcd / NXCD);
    int nhi = (int)((long long)N * (xcd + 1) / NXCD);
    int stride = nsl * blockDim.x;
    int tid = sl * blockDim.x + threadIdx.x;
    for (int eb = tid; eb < E; eb += stride * 4) {
        int dd[4], ss[4];
#pragma unroll
        for (int u = 0; u < 4; u++) {
            int e = eb + u * stride;
            bool ok = e < E;
            dd[u] = ok ? ei[E + e] : -1;
            ss[u] = ok ? ei[e] : 0;
        }
#pragma unroll
        for (int u = 0; u < 4; u++) {
            int d = dd[u];
            if (d >= nlo && d < nhi) {
                int pos = atomicAdd(&cnt[d], 1);
                csr[(d << 6) + pos] = ss[u];
            }
        }
    }
}

// node_rec {deg, dinv_bits, batch, 0} + pre-scaled xs + zero pad rows + graph
// bounds (from sorted batch) -- one streaming pass, NO atomics.
__global__ void prep_kernel(const int* __restrict__ cnt, const float* __restrict__ x,
                            const int* __restrict__ batch, int4* __restrict__ rec,
                            float* __restrict__ xs, int* __restrict__ gb,
                            uint2* __restrict__ padA, uint2* __restrict__ padB, int N, int G) {
    int gid = blockIdx.x * blockDim.x + threadIdx.x;
    if (gid < 16) {
        padA[gid] = make_uint2(0u, 0u);
        padB[gid] = make_uint2(0u, 0u);
    }
    int stride = gridDim.x * blockDim.x;
    for (int n = gid; n < N; n += stride) {
        int deg = cnt[n];
        float dn = rsqrtf((float)(deg + 1));  // +1 self-loop
        int b = batch[n];
        rec[n] = make_int4(deg, __float_as_int(dn), b, 0);
        xs[n] = dn * x[n];
        // graph bounds: gb[g] = first node with batch >= g; gb[G] = N
        if (n == 0) {
            for (int g = 0; g <= b; g++) gb[g] = 0;
        } else {
            int pb = batch[n - 1];
            for (int g = pb + 1; g <= b; g++) gb[g] = n;
        }
        if (n == N - 1) {
            for (int g = b + 1; g <= G; g++) gb[g] = N;
        }
    }
}

// ---------------- piecewise-linear table for layer1 composite ----------------

__global__ void table_kernel(const float* __restrict__ W1, const float* __restrict__ b1,
                             const float* __restrict__ W2, float* __restrict__ tsort,
                             float* __restrict__ tabA, float* __restrict__ tabB) {
    int j = threadIdx.x;  // 64 threads = 1 wave
    float a = W1[j], b = b1[j];
    float t = (a != 0.f) ? (-b / a) : 3.4e38f;
    int rank = 0;
#pragma unroll 8
    for (int k = 0; k < 64; k++) {
        float tk = __shfl(t, k);
        rank += (tk < t) || (tk == t && k < j);
    }
    __shared__ float st[64];
    __shared__ int sperm[64];
    st[rank] = t;
    sperm[rank] = j;
    __syncthreads();
    tsort[j] = st[j];
    int f = j;
    float A = 0.f, B = 0.f;
#pragma unroll 4
    for (int k = 0; k < 64; k++) {
        float ak = W1[k], bk = b1[k], w = W2[k * 64 + f];
        if (ak < 0.f) { A += ak * w; B += bk * w; }
        else if (ak == 0.f && bk > 0.f) { B += bk * w; }
    }
    tabA[f] = A;
    tabB[f] = B;
#pragma unroll 4
    for (int s = 1; s <= 64; s++) {
        int jj = sperm[s - 1];
        float aj = W1[jj], bj = b1[jj], w = W2[jj * 64 + f];
        if (aj > 0.f) { A += aj * w; B += bj * w; }
        else if (aj < 0.f) { A -= aj * w; B -= bj * w; }
        tabA[s * 64 + f] = A;
        tabB[s * 64 + f] = B;
    }
}

// ---------------- LDS weight staging + packed quarter-split matmul ----------------

__device__ __forceinline__ void stageW(const float* __restrict__ W, float* __restrict__ sW) {
    for (int i = threadIdx.x; i < HID * HID; i += 256) {
        int r = i >> 6, c = i & 63;
        sW[r * WPAD + c] = W[i];
    }
    __syncthreads();
}

__device__ __forceinline__ void qmatmul(float4 h4, const float* __restrict__ sW, int q, int sl,
                                        v2f& z0, v2f& z1) {
    z0 = (v2f){0.f, 0.f};
    z1 = (v2f){0.f, 0.f};
#pragma unroll
    for (int t = 0; t < 16; t++) {
        int k = (q << 4) + t;
        int srclane = 20 * q + (t >> 2);
        float comp = ((t & 3) == 0) ? h4.x : ((t & 3) == 1) ? h4.y : ((t & 3) == 2) ? h4.z : h4.w;
        float hk = __shfl(comp, srclane);
        const v2f* w2 = reinterpret_cast<const v2f*>(&sW[k * WPAD + sl * 4]);
        z0 += hk * w2[0];  // v_pk_fma_f32
        z1 += hk * w2[1];
    }
#pragma unroll
    for (int off = 16; off <= 32; off <<= 1) {
        z0.x += __shfl_xor(z0.x, off);
        z0.y += __shfl_xor(z0.y, off);
        z1.x += __shfl_xor(z1.x, off);
        z1.y += __shfl_xor(z1.y, off);
    }
}

// ---------------- Layer 1: scalar propagate + table lookup -> bf16 z' ----------------

__global__ __launch_bounds__(256) void layer1_kernel(
    const float* __restrict__ xs, const int* __restrict__ csr, const int4* __restrict__ rec,
    const float* __restrict__ tsort, const float* __restrict__ tabA,
    const float* __restrict__ tabB, char* __restrict__ zb, int N) {
    int lane = threadIdx.x & 63;
    float tl = tsort[lane];  // one sorted breakpoint per lane
    int n = blockIdx.x * 4 + (threadIdx.x >> 6);
    if (n >= N) return;
    const int4 r = rec[n];
    float dn = __int_as_float(r.y);
    float acc = (lane < r.x) ? xs[csr[(n << 6) + lane]] : 0.f;
#pragma unroll
    for (int off = 32; off; off >>= 1) acc += __shfl_xor(acc, off);
    float p = dn * (acc + xs[n]);  // wave-uniform
    int s = __popcll(__ballot(tl <= p));
    float zf = dn * (p * tabA[s * 64 + lane] + tabB[s * 64 + lane]);
    float zo = __shfl_xor(zf, 1);  // partner feature
    if (!(lane & 1))
        *reinterpret_cast<unsigned*>(zb + (((size_t)n) << 7) + ((lane >> 1) << 2)) =
            packbf(zf, zo);
}

// ---------------- dual-node 64-wide propagate, 6-deep unroll ----------------
// 2 nodes/wave x 6-deep inner unroll = 12 independent gathers in flight at
// ~44-48 VGPR -> stays under the 64-VGPR occupancy cliff.
// FUSE: out' = dinv * (relu(P+bias) @ W) -> bf16   (layer 2)
// POOL: segmented LDS reduce over the block's 8 sorted nodes + fp32 atomic runs

template <bool FUSE, bool POOL>
__global__ __launch_bounds__(256) void p64_kernel(
    const char* __restrict__ zbase, const int* __restrict__ csr, const int4* __restrict__ rec,
    const float* __restrict__ bias, const float* __restrict__ W,
    uint2* __restrict__ outb, float* __restrict__ outp, int N) {
    __shared__ float sW[FUSE ? HID * WPAD : 1];
    __shared__ float pbuf[POOL ? 8 : 1][POOL ? HID : 1];
    __shared__ int pg[8];
    if (FUSE) stageW(W, sW);
    int lane = threadIdx.x & 63;
    int wid = threadIdx.x >> 6;
    int q = lane >> 4, sl = lane & 15;
    int nA = blockIdx.x * 8 + wid * 2;
    int nB = nA + 1;
    bool vA = nA < N, vB = nB < N;
    if (!POOL && !vA) return;
    unsigned soff = (unsigned)(sl << 3);

    int degA = vA ? rec[nA].x : 0;
    int degB = vB ? rec[nB].x : 0;
    int ewA = (lane < degA) ? csr[((vA ? nA : 0) << 6) + lane] : N;
    int ewB = (lane < degB) ? csr[((vB ? nB : 0) << 6) + lane] : N;
    int mtA = (degA + 3) >> 2, mtB = (degB + 3) >> 2;
    int mtmax = max(mtA, mtB);

    v2f a0A = {0.f, 0.f}, a1A = {0.f, 0.f};
    v2f a0B = {0.f, 0.f}, a1B = {0.f, 0.f};
    for (int tb = 0; tb < mtmax; tb += 6) {
#pragma unroll
        for (int u = 0; u < 6; u++) {
            int t = tb + u;
            int eidx = ((t << 2) + q) & 63;
            int sA = __shfl(ewA, eidx);
            int sB = __shfl(ewB, eidx);
            sA = (t < mtA) ? sA : N;  // wave-uniform predicate -> zero row
            sB = (t < mtB) ? sB : N;
            const uint2 ra = *reinterpret_cast<const uint2*>(
                zbase + (((unsigned)sA << 7) + soff));
            const uint2 rb = *reinterpret_cast<const uint2*>(
                zbase + (((unsigned)sB << 7) + soff));
            v2f u0 = {bflo(ra.x), bfhi(ra.x)};
            v2f u1 = {bflo(ra.y), bfhi(ra.y)};
            a0A += u0; a1A += u1;
            v2f w0 = {bflo(rb.x), bfhi(rb.x)};
            v2f w1 = {bflo(rb.y), bfhi(rb.y)};
            a0B += w0; a1B += w1;
        }
    }
#pragma unroll
    for (int off = 16; off <= 32; off <<= 1) {
        a0A.x += __shfl_xor(a0A.x, off); a0A.y += __shfl_xor(a0A.y, off);
        a1A.x += __shfl_xor(a1A.x, off); a1A.y += __shfl_xor(a1A.y, off);
        a0B.x += __shfl_xor(a0B.x, off); a0B.y += __shfl_xor(a0B.y, off);
        a1B.x += __shfl_xor(a1B.x, off); a1B.y += __shfl_xor(a1B.y, off);
    }
    // self terms (pre-scaled) + dinv[d] scale; rec reloaded post-loop (L2-hot)
    float dnA = __int_as_float(rec[vA ? nA : 0].y);
    float dnB = __int_as_float(rec[vB ? nB : 0].y);
    {
        const uint2 sa = *reinterpret_cast<const uint2*>(
            zbase + (((unsigned)(vA ? nA : N) << 7) + soff));
        a0A.x = dnA * (a0A.x + bflo(sa.x));
        a0A.y = dnA * (a0A.y + bfhi(sa.x));
        a1A.x = dnA * (a1A.x + bflo(sa.y));
        a1A.y = dnA * (a1A.y + bfhi(sa.y));
        const uint2 sb = *reinterpret_cast<const uint2*>(
            zbase + (((unsigned)(vB ? nB : N) << 7) + soff));
        a0B.x = dnB * (a0B.x + bflo(sb.x));
        a0B.y = dnB * (a0B.y + bfhi(sb.x));
        a1B.x = dnB * (a1B.x + bflo(sb.y));
        a1B.y = dnB * (a1B.y + bfhi(sb.y));
    }
    const float4 b4 = *reinterpret_cast<const float4*>(&bias[sl << 2]);

    if (FUSE) {
        float4 hA, hB;
        hA.x = fmaxf(a0A.x + b4.x, 0.f); hA.y = fmaxf(a0A.y + b4.y, 0.f);
        hA.z = fmaxf(a1A.x + b4.z, 0.f); hA.w = fmaxf(a1A.y + b4.w, 0.f);
        hB.x = fmaxf(a0B.x + b4.x, 0.f); hB.y = fmaxf(a0B.y + b4.y, 0.f);
        hB.z = fmaxf(a1B.x + b4.z, 0.f); hB.w = fmaxf(a1B.y + b4.w, 0.f);
        v2f zA0, zA1, zB0, zB1;
        qmatmul(hA, sW, q, sl, zA0, zA1);
        qmatmul(hB, sW, q, sl, zB0, zB1);
        if (q == 0) {
            if (vA)
                outb[(size_t)nA * 16 + sl] = make_uint2(packbf(dnA * zA0.x, dnA * zA0.y),
                                                        packbf(dnA * zA1.x, dnA * zA1.y));
            if (vB)
                outb[(size_t)nB * 16 + sl] = make_uint2(packbf(dnB * zB0.x, dnB * zB0.y),
                                                        packbf(dnB * zB1.x, dnB * zB1.y));
        }
    } else if (POOL) {
        if (q == 0) {
            *reinterpret_cast<float4*>(&pbuf[wid * 2][sl << 2]) =
                make_float4(a0A.x + b4.x, a0A.y + b4.y, a1A.x + b4.z, a1A.y + b4.w);
            *reinterpret_cast<float4*>(&pbuf[wid * 2 + 1][sl << 2]) =
                make_float4(a0B.x + b4.x, a0B.y + b4.y, a1B.x + b4.z, a1B.y + b4.w);
            if (sl == 0) {
                pg[wid * 2] = vA ? rec[nA].z : -1;
                pg[wid * 2 + 1] = vB ? rec[nB].z : -1;
            }
        }
        __syncthreads();
        if (wid == 0) {
            int j = lane;
            float v = 0.f;
            int gp = -1;
#pragma unroll
            for (int w = 0; w < 8; w++) {
                int gw = pg[w];  // wave-uniform
                if (gw < 0) continue;
                if (gw == gp) {
                    v += pbuf[w][j];
                } else {
                    if (gp >= 0) atomicAdd(&outp[(size_t)gp * HID + j], v);
                    v = pbuf[w][j];
                    gp = gw;
                }
            }
            if (gp >= 0) atomicAdd(&outp[(size_t)gp * HID + j], v);
        }
    }
}

// ---------------- head (counts from graph bounds) ----------------

__global__ void head_kernel(const float* __restrict__ psum, const int* __restrict__ gb,
                            const float* __restrict__ dist, const float* __restrict__ sw,
                            const float* __restrict__ Wl, const float* __restrict__ bl,
                            const float* __restrict__ Wl1, const float* __restrict__ bl1,
                            const float* __restrict__ Wl2, const float* __restrict__ bl2,
                            float* __restrict__ out, int G) {
    int g = blockIdx.x * blockDim.x + threadIdx.x;
    if (g >= G) return;
    int c = gb[g + 1] - gb[g];
    float invc = 1.f / fmaxf((float)c, 1.f);
    float a[5];
#pragma unroll
    for (int k = 0; k < 5; k++) a[k] = bl[k];
    for (int j = 0; j < HID; j++) {
        float p = psum[(size_t)g * HID + j] * invc;
#pragma unroll
        for (int k = 0; k < 5; k++) a[k] += p * Wl[j * 5 + k];
    }
    float g7[7];
#pragma unroll
    for (int k = 0; k < 5; k++) g7[k] = a[k];
    g7[5] = dist[g];
    g7[6] = sw[g];
    float r = bl2[0];
#pragma unroll
    for (int k2 = 0; k2 < 5; k2++) {
        float t = bl1[k2];
#pragma unroll
        for (int j = 0; j < 7; j++) t += g7[j] * Wl1[j * 5 + k2];
        t = fmaxf(t, 0.f);
        r += t * Wl2[k2];
    }
    out[g] = r;
}

// ---------------- launch ----------------

extern "C" void kernel_launch(void* const* d_in, const int* in_sizes, int n_in,
                              void* d_out, int out_size, void* d_ws, size_t ws_size,
                              hipStream_t stream) {
    const float* x    = (const float*)d_in[0];
    const int*   ei   = (const int*)d_in[1];
    const int*   batch= (const int*)d_in[2];
    const float* dist = (const float*)d_in[3];
    const float* sw   = (const float*)d_in[4];
    const float* W1   = (const float*)d_in[5];
    const float* b1   = (const float*)d_in[6];
    const float* W2   = (const float*)d_in[7];
    const float* b2   = (const float*)d_in[8];
    const float* W3   = (const float*)d_in[9];
    const float* b3   = (const float*)d_in[10];
    const float* Wl   = (const float*)d_in[11];
    const float* bl   = (const float*)d_in[12];
    const float* Wl1  = (const float*)d_in[13];
    const float* bl1  = (const float*)d_in[14];
    const float* Wl2  = (const float*)d_in[15];
    const float* bl2  = (const float*)d_in[16];

    int N = in_sizes[0];
    int E = in_sizes[1] / 2;
    int G = in_sizes[3];

    char* ws = (char*)d_ws;
    size_t off = 0;
    auto alloc = [&](size_t bytes) -> char* {
        char* p = ws + off;
        off += (bytes + 255) & ~(size_t)255;
        return p;
    };
    // contiguous zero-init region: cnt | psum
    char*  zreg      = ws;
    int*   cnt       = (int*)alloc((size_t)N * 4);
    float* psum      = (float*)alloc((size_t)G * HID * 4);
    size_t zbytes    = off;
    int4*  rec       = (int4*)alloc((size_t)N * 16);
    float* xs        = (float*)alloc((size_t)N * 4);
    int*   gb        = (int*)alloc(((size_t)G + 1) * 4);
    float* tsort     = (float*)alloc(64 * 4);
    float* tabA      = (float*)alloc(65 * 64 * 4);
    float* tabB      = (float*)alloc(65 * 64 * 4);
    char*  bufA      = alloc(((size_t)N + 1) * 128);   // bf16 rows + zero pad row N
    char*  bufB      = alloc(((size_t)N + 1) * 128);
    int*   csr       = (int*)alloc((size_t)N * 64 * 4);  // fixed-cap CSR, 64 slots/node

    (void)hipMemsetAsync(zreg, 0, zbytes, stream);

    table_kernel<<<1, 64, 0, stream>>>(W1, b1, W2, tsort, tabA, tabB);
    fill_part<<<2048, 256, 0, stream>>>(ei, E, N, cnt, csr);
    prep_kernel<<<(N + 255) / 256, 256, 0, stream>>>(
        cnt, x, batch, rec, xs, gb,
        (uint2*)(bufA + (size_t)N * 128), (uint2*)(bufB + (size_t)N * 128), N, G);

    int nb1 = (N + 3) / 4;
    int nb2 = (N + 7) / 8;
    layer1_kernel<<<nb1, 256, 0, stream>>>(xs, csr, rec, tsort, tabA, tabB, bufA, N);
    p64_kernel<true, false><<<nb2, 256, 0, stream>>>(bufA, csr, rec, b2, W3,
                                                     (uint2*)bufB, nullptr, N);
    p64_kernel<false, true><<<nb2, 256, 0, stream>>>(bufB, csr, rec, b3, nullptr,
                                                     nullptr, psum, N);
    head_kernel<<<(G + 255) / 256, 256, 0, stream>>>(psum, gb, dist, sw, Wl, bl, Wl1, bl1, Wl2,
                                                     bl2, (float*)d_out, G);
}